// Round 1
// baseline (2251.632 us; speedup 1.0000x reference)
//
#include <hip/hip_runtime.h>

#define N_NODES 100000
#define T_P 12
#define C_H 32
#define E_EDGES 3200000

// ws layout (floats):
//   [0..255]    params P: [0..11] probs, [16..47] A_z, [48..79] B_z, [80..111] A_h, [112..143] B_h
//   [256 .. 256+N)           deg -> dinv (in place)
//   [256+N .. 256+N+N*T)     agg
#define WS_P      0
#define WS_DEG    256
#define WS_AGG    (256 + N_NODES)

__global__ void init_kernel(float* __restrict__ deg, float* __restrict__ agg) {
    int i = blockIdx.x * blockDim.x + threadIdx.x;
    if (i < N_NODES) deg[i] = 1.0f;            // self-loop weight 1 pre-added
    if (i < N_NODES * T_P) agg[i] = 0.0f;
}

__global__ void params_kernel(const float* __restrict__ wz, const float* __restrict__ bz,
                              const float* __restrict__ wh, const float* __restrict__ bh,
                              const float* __restrict__ lwz, const float* __restrict__ lbz,
                              const float* __restrict__ lwh, const float* __restrict__ lbh,
                              const float* __restrict__ att, float* __restrict__ P) {
    int o = threadIdx.x;
    if (o < C_H) {
        float az = 0.f, bzv = 0.f, ah = 0.f, bhv = 0.f;
        for (int c = 0; c < C_H; ++c) {
            float lz = lwz[o * 2 * C_H + c];
            float lh = lwh[o * 2 * C_H + c];
            az += wz[c] * lz;  bzv += bz[c] * lz;
            ah += wh[c] * lh;  bhv += bh[c] * lh;
        }
        P[16 + o]  = az;  P[48 + o]  = bzv + lbz[o];
        P[80 + o]  = ah;  P[112 + o] = bhv + lbh[o];
    }
    if (o == 0) {
        float m = -1e30f;
        for (int t = 0; t < T_P; ++t) m = fmaxf(m, att[t]);
        float e[T_P], s = 0.f;
        for (int t = 0; t < T_P; ++t) { e[t] = __expf(att[t] - m); s += e[t]; }
        float inv = 1.0f / s;
        for (int t = 0; t < T_P; ++t) P[t] = e[t] * inv;
    }
}

__global__ void deg_kernel(const int* __restrict__ dst, const float* __restrict__ w,
                           float* __restrict__ deg) {
    int e = blockIdx.x * blockDim.x + threadIdx.x;
    if (e < E_EDGES) unsafeAtomicAdd(&deg[dst[e]], w[e]);
}

__global__ void dinv_kernel(float* __restrict__ deg) {
    int i = blockIdx.x * blockDim.x + threadIdx.x;
    if (i < N_NODES) {
        float d = deg[i];
        deg[i] = (d > 0.f) ? rsqrtf(d) : 0.f;
    }
}

__global__ void scatter_kernel(const int* __restrict__ src, const int* __restrict__ dst,
                               const float* __restrict__ w, const float* __restrict__ dinv,
                               const float* __restrict__ x, float* __restrict__ agg) {
    int e = blockIdx.x * blockDim.x + threadIdx.x;
    if (e >= E_EDGES) return;
    int s = src[e], d = dst[e];
    float nrm = dinv[s] * w[e] * dinv[d];
    const float4* xs = (const float4*)(x + (size_t)s * T_P);  // 48B offset: 16B aligned
    float4 x0 = xs[0], x1 = xs[1], x2 = xs[2];
    float* ad = agg + (size_t)d * T_P;
    unsafeAtomicAdd(ad + 0,  nrm * x0.x);
    unsafeAtomicAdd(ad + 1,  nrm * x0.y);
    unsafeAtomicAdd(ad + 2,  nrm * x0.z);
    unsafeAtomicAdd(ad + 3,  nrm * x0.w);
    unsafeAtomicAdd(ad + 4,  nrm * x1.x);
    unsafeAtomicAdd(ad + 5,  nrm * x1.y);
    unsafeAtomicAdd(ad + 6,  nrm * x1.z);
    unsafeAtomicAdd(ad + 7,  nrm * x1.w);
    unsafeAtomicAdd(ad + 8,  nrm * x2.x);
    unsafeAtomicAdd(ad + 9,  nrm * x2.y);
    unsafeAtomicAdd(ad + 10, nrm * x2.z);
    unsafeAtomicAdd(ad + 11, nrm * x2.w);
}

__global__ void final_kernel(const float* __restrict__ x, const float* __restrict__ dinv,
                             const float* __restrict__ agg, const float* __restrict__ P,
                             const float* __restrict__ head_w, const float* __restrict__ head_b,
                             float* __restrict__ out) {
    int tid = blockIdx.x * blockDim.x + threadIdx.x;
    int n = tid >> 5;         // 32 lanes per node (channel o = lane)
    int o = tid & 31;
    if (n >= N_NODES) return;
    float Az = P[16 + o], Bz = P[48 + o], Ah = P[80 + o], Bh = P[112 + o];
    float di = dinv[n];
    float sl = di * di;       // self-loop norm: dinv[n]*1*dinv[n]
    float h = 0.f;
#pragma unroll
    for (int t = 0; t < T_P; ++t) {
        float a = agg[(size_t)n * T_P + t] + sl * x[(size_t)n * T_P + t];
        float z  = 1.f / (1.f + __expf(-(a * Az + Bz)));
        float th = tanhf(a * Ah + Bh);
        h += P[t] * (1.f - z) * th;
    }
    h = fmaxf(h, 0.f) * head_w[o];
#pragma unroll
    for (int m = 16; m > 0; m >>= 1) h += __shfl_xor(h, m, 32);
    if (o == 0) out[n] = h + head_b[0];
}

extern "C" void kernel_launch(void* const* d_in, const int* in_sizes, int n_in,
                              void* d_out, int out_size, void* d_ws, size_t ws_size,
                              hipStream_t stream) {
    const float* x    = (const float*)d_in[0];
    const int*   ei   = (const int*)d_in[1];      // [2, E]: src = ei, dst = ei + E
    const float* ew   = (const float*)d_in[2];
    const float* w_z  = (const float*)d_in[3];
    const float* b_z  = (const float*)d_in[4];
    const float* w_h  = (const float*)d_in[7];
    const float* b_h  = (const float*)d_in[8];
    const float* lw_z = (const float*)d_in[9];
    const float* lb_z = (const float*)d_in[10];
    const float* lw_h = (const float*)d_in[13];
    const float* lb_h = (const float*)d_in[14];
    const float* att  = (const float*)d_in[15];
    const float* hw   = (const float*)d_in[16];
    const float* hb   = (const float*)d_in[17];
    float* out = (float*)d_out;

    float* wsf  = (float*)d_ws;
    float* P    = wsf + WS_P;
    float* deg  = wsf + WS_DEG;   // becomes dinv in place
    float* agg  = wsf + WS_AGG;

    const int* src = ei;
    const int* dst = ei + E_EDGES;

    // 1) init deg=1 (self-loop), agg=0
    {
        int total = N_NODES * T_P;
        init_kernel<<<(total + 255) / 256, 256, 0, stream>>>(deg, agg);
    }
    // 2) fold gate weights + softmax(att)
    params_kernel<<<1, 64, 0, stream>>>(w_z, b_z, w_h, b_h, lw_z, lb_z, lw_h, lb_h, att, P);
    // 3) degree scatter
    deg_kernel<<<(E_EDGES + 255) / 256, 256, 0, stream>>>(dst, ew, deg);
    // 4) dinv = rsqrt(deg)
    dinv_kernel<<<(N_NODES + 255) / 256, 256, 0, stream>>>(deg);
    // 5) agg scatter: agg[d,t] += dinv[s]*w*dinv[d] * x[s,t]
    scatter_kernel<<<(E_EDGES + 255) / 256, 256, 0, stream>>>(src, dst, ew, deg, x, agg);
    // 6) fused gates + attention + relu + head
    {
        int total = N_NODES * C_H;
        final_kernel<<<(total + 255) / 256, 256, 0, stream>>>(x, deg, agg, P, hw, hb, out);
    }
}

// Round 2
// 455.136 us; speedup vs baseline: 4.9472x; 4.9472x over previous
//
#include <hip/hip_runtime.h>

#define N_NODES 100000
#define T_P 12
#define C_H 32
#define E_EDGES 3200000
#define NB_SCAN 98   // ceil(100000/1024)

// ws layout (4-byte units from d_ws):
//   P[256] | dinv[N] | agg[N*T] | count[N] | offs[N+2] | partial[128] | r[E] | csr[E]{float2}
// total ~44.4 MB

__global__ void init_kernel(int* __restrict__ count) {
    int i = blockIdx.x * blockDim.x + threadIdx.x;
    if (i < N_NODES) count[i] = 0;
}

__global__ void params_kernel(const float* __restrict__ wz, const float* __restrict__ bz,
                              const float* __restrict__ wh, const float* __restrict__ bh,
                              const float* __restrict__ lwz, const float* __restrict__ lbz,
                              const float* __restrict__ lwh, const float* __restrict__ lbh,
                              const float* __restrict__ att, float* __restrict__ P) {
    int o = threadIdx.x;
    if (o < C_H) {
        float az = 0.f, bzv = 0.f, ah = 0.f, bhv = 0.f;
        for (int c = 0; c < C_H; ++c) {
            float lz = lwz[o * 2 * C_H + c];
            float lh = lwh[o * 2 * C_H + c];
            az += wz[c] * lz;  bzv += bz[c] * lz;
            ah += wh[c] * lh;  bhv += bh[c] * lh;
        }
        P[16 + o]  = az;  P[48 + o]  = bzv + lbz[o];
        P[80 + o]  = ah;  P[112 + o] = bhv + lbh[o];
    }
    if (o == 0) {
        float m = -1e30f;
        for (int t = 0; t < T_P; ++t) m = fmaxf(m, att[t]);
        float e[T_P], s = 0.f;
        for (int t = 0; t < T_P; ++t) { e[t] = __expf(att[t] - m); s += e[t]; }
        float inv = 1.0f / s;
        for (int t = 0; t < T_P; ++t) P[t] = e[t] * inv;
    }
}

// r[e] = rank of edge e within its destination bucket
__global__ void rank_kernel(const int* __restrict__ dst, int* __restrict__ count,
                            int* __restrict__ r) {
    int e = blockIdx.x * blockDim.x + threadIdx.x;
    if (e < E_EDGES) r[e] = atomicAdd(&count[dst[e]], 1);
}

// block-level exclusive scan of count -> offs, block totals -> partial
__global__ void scan_blocks(const int* __restrict__ count, int* __restrict__ offs,
                            int* __restrict__ partial) {
    __shared__ int buf[1024];
    int i = blockIdx.x * 1024 + threadIdx.x;
    int v = (i < N_NODES) ? count[i] : 0;
    buf[threadIdx.x] = v;
    __syncthreads();
    for (int d = 1; d < 1024; d <<= 1) {
        int t = (threadIdx.x >= d) ? buf[threadIdx.x - d] : 0;
        __syncthreads();
        buf[threadIdx.x] += t;
        __syncthreads();
    }
    if (i < N_NODES) offs[i] = buf[threadIdx.x] - v;   // exclusive
    if (threadIdx.x == 1023) partial[blockIdx.x] = buf[1023];
}

__global__ void scan_partials(int* __restrict__ partial) {
    __shared__ int buf[128];
    int tid = threadIdx.x;
    int v = (tid < NB_SCAN) ? partial[tid] : 0;
    buf[tid] = v;
    __syncthreads();
    for (int d = 1; d < 128; d <<= 1) {
        int t = (tid >= d) ? buf[tid - d] : 0;
        __syncthreads();
        buf[tid] += t;
        __syncthreads();
    }
    if (tid < NB_SCAN) partial[tid] = buf[tid] - v;    // exclusive block bases
}

__global__ void add_base(int* __restrict__ offs, const int* __restrict__ partial) {
    int i = blockIdx.x * 1024 + threadIdx.x;
    if (i < N_NODES) offs[i] += partial[blockIdx.x];
    if (i == 0) offs[N_NODES] = E_EDGES;
}

// csr[offs[dst]+r] = {src_bits, w} — no atomics
__global__ void fill_kernel(const int* __restrict__ src, const int* __restrict__ dst,
                            const float* __restrict__ w, const int* __restrict__ offs,
                            const int* __restrict__ r, float2* __restrict__ csr) {
    int e = blockIdx.x * blockDim.x + threadIdx.x;
    if (e >= E_EDGES) return;
    int pos = offs[dst[e]] + r[e];
    csr[pos] = make_float2(__int_as_float(src[e]), w[e]);
}

// dinv[n] = rsqrt(1 + sum of incoming weights)
__global__ void degree_kernel(const int* __restrict__ offs, const float2* __restrict__ csr,
                              float* __restrict__ dinv) {
    int n = blockIdx.x * blockDim.x + threadIdx.x;
    if (n >= N_NODES) return;
    int b = offs[n], e = offs[n + 1];
    float s = 1.0f;                         // self-loop weight
    for (int i = b; i < e; ++i) s += csr[i].y;
    dinv[n] = rsqrtf(s);
}

// agg[n,t] = dinv[n] * ( dinv[n]*x[n,t] + sum_e w_e*dinv[s_e]*x[s_e,t] )
__global__ void gather_kernel(const int* __restrict__ offs, const float2* __restrict__ csr,
                              const float* __restrict__ dinv, const float* __restrict__ x,
                              float* __restrict__ agg) {
    int n = blockIdx.x * blockDim.x + threadIdx.x;
    if (n >= N_NODES) return;
    int b = offs[n], e = offs[n + 1];
    float din = dinv[n];
    const float4* xn = (const float4*)(x + (size_t)n * T_P);
    float4 a0 = xn[0], a1 = xn[1], a2 = xn[2];
    a0.x *= din; a0.y *= din; a0.z *= din; a0.w *= din;
    a1.x *= din; a1.y *= din; a1.z *= din; a1.w *= din;
    a2.x *= din; a2.y *= din; a2.z *= din; a2.w *= din;
    for (int i = b; i < e; ++i) {
        float2 sw = csr[i];
        int s = __float_as_int(sw.x);
        float coef = sw.y * dinv[s];
        const float4* xs = (const float4*)(x + (size_t)s * T_P);
        float4 x0 = xs[0], x1 = xs[1], x2 = xs[2];
        a0.x += coef * x0.x; a0.y += coef * x0.y; a0.z += coef * x0.z; a0.w += coef * x0.w;
        a1.x += coef * x1.x; a1.y += coef * x1.y; a1.z += coef * x1.z; a1.w += coef * x1.w;
        a2.x += coef * x2.x; a2.y += coef * x2.y; a2.z += coef * x2.z; a2.w += coef * x2.w;
    }
    a0.x *= din; a0.y *= din; a0.z *= din; a0.w *= din;
    a1.x *= din; a1.y *= din; a1.z *= din; a1.w *= din;
    a2.x *= din; a2.y *= din; a2.z *= din; a2.w *= din;
    float4* an = (float4*)(agg + (size_t)n * T_P);
    an[0] = a0; an[1] = a1; an[2] = a2;
}

__global__ void final_kernel(const float* __restrict__ agg, const float* __restrict__ P,
                             const float* __restrict__ head_w, const float* __restrict__ head_b,
                             float* __restrict__ out) {
    int tid = blockIdx.x * blockDim.x + threadIdx.x;
    int n = tid >> 5;         // 32 lanes per node (channel o = lane)
    int o = tid & 31;
    if (n >= N_NODES) return;
    float Az = P[16 + o], Bz = P[48 + o], Ah = P[80 + o], Bh = P[112 + o];
    float h = 0.f;
#pragma unroll
    for (int t = 0; t < T_P; ++t) {
        float a = agg[(size_t)n * T_P + t];
        float oz = 1.f / (1.f + __expf(a * Az + Bz));          // 1 - sigmoid(u) = sigmoid(-u)
        float v  = a * Ah + Bh;
        float th = 1.f - 2.f / (1.f + __expf(2.f * v));        // tanh via exp
        h += P[t] * oz * th;
    }
    h = fmaxf(h, 0.f) * head_w[o];
#pragma unroll
    for (int m = 16; m > 0; m >>= 1) h += __shfl_xor(h, m, 32);
    if (o == 0) out[n] = h + head_b[0];
}

extern "C" void kernel_launch(void* const* d_in, const int* in_sizes, int n_in,
                              void* d_out, int out_size, void* d_ws, size_t ws_size,
                              hipStream_t stream) {
    const float* x    = (const float*)d_in[0];
    const int*   ei   = (const int*)d_in[1];      // [2, E]: src = ei, dst = ei + E
    const float* ew   = (const float*)d_in[2];
    const float* w_z  = (const float*)d_in[3];
    const float* b_z  = (const float*)d_in[4];
    const float* w_h  = (const float*)d_in[7];
    const float* b_h  = (const float*)d_in[8];
    const float* lw_z = (const float*)d_in[9];
    const float* lb_z = (const float*)d_in[10];
    const float* lw_h = (const float*)d_in[13];
    const float* lb_h = (const float*)d_in[14];
    const float* att  = (const float*)d_in[15];
    const float* hw   = (const float*)d_in[16];
    const float* hb   = (const float*)d_in[17];
    float* out = (float*)d_out;

    float* wsf    = (float*)d_ws;
    float* P      = wsf;                       // 256
    float* dinv   = P + 256;                   // N
    float* agg    = dinv + N_NODES;            // N*T
    int*   count  = (int*)(agg + (size_t)N_NODES * T_P);   // N
    int*   offs   = count + N_NODES;           // N+2 (padded for float2 alignment)
    int*   partial= offs + N_NODES + 2;        // 128
    int*   r      = partial + 128;             // E
    float2* csr   = (float2*)(r + E_EDGES);    // E

    const int* src = ei;
    const int* dst = ei + E_EDGES;

    init_kernel<<<(N_NODES + 255) / 256, 256, 0, stream>>>(count);
    params_kernel<<<1, 64, 0, stream>>>(w_z, b_z, w_h, b_h, lw_z, lb_z, lw_h, lb_h, att, P);
    rank_kernel<<<(E_EDGES + 255) / 256, 256, 0, stream>>>(dst, count, r);
    scan_blocks<<<NB_SCAN, 1024, 0, stream>>>(count, offs, partial);
    scan_partials<<<1, 128, 0, stream>>>(partial);
    add_base<<<NB_SCAN, 1024, 0, stream>>>(offs, partial);
    fill_kernel<<<(E_EDGES + 255) / 256, 256, 0, stream>>>(src, dst, ew, offs, r, csr);
    degree_kernel<<<(N_NODES + 255) / 256, 256, 0, stream>>>(offs, csr, dinv);
    gather_kernel<<<(N_NODES + 255) / 256, 256, 0, stream>>>(offs, csr, dinv, x, agg);
    final_kernel<<<(N_NODES * C_H + 255) / 256, 256, 0, stream>>>(agg, P, hw, hb, out);
}